// Round 1
// baseline (1696.957 us; speedup 1.0000x reference)
//
#include <hip/hip_runtime.h>

#define HID    128
#define NTREES 8
#define DEPTH  15
#define TNODES 32767
#define TM     16

__device__ __forceinline__ float fast_sigmoid(float x) {
  return __builtin_amdgcn_rcpf(1.0f + __expf(-x));
}
__device__ __forceinline__ float fast_tanh(float x) {
  // tanh(x) = 1 - 2/(exp(2x)+1); saturates correctly for |x| large.
  return 1.0f - 2.0f * __builtin_amdgcn_rcpf(1.0f + __expf(2.0f * x));
}

// One level of the tree, fused: emb-gather + emb@W_iou (+ h_tild@U_iou + f-gates) + LSTM cell.
// Block: 256 threads, TM=16 nodes. h lives in d_out, c in d_ws.
template <bool LEAF>
__global__ __launch_bounds__(256)
void tree_level_kernel(const int* __restrict__ wordid,
                       const int* __restrict__ mask,
                       const float* __restrict__ c_init,
                       const float* __restrict__ emb_table,
                       const float* __restrict__ W_iou,
                       const float* __restrict__ U_iou,
                       const float* __restrict__ b_iou,
                       const float* __restrict__ U_f_w,
                       const float* __restrict__ U_f_b,
                       float* __restrict__ h_out,
                       float* __restrict__ c_buf,
                       int level)
{
  const int nl = 1 << level;
  const int ps = nl - 1;
  const int R  = NTREES << level;   // rows (nodes) at this level across trees
  const int tid = threadIdx.x;
  const int r0  = blockIdx.x * TM;

  // Phase-1 layout: emb[TM][128] | hch[2TM][128] | htild[TM][128]  (32 KB)
  // Phase-2 overlay: iou[TM][384] | f[2TM][128]                    (40 KB)
  __shared__ __align__(16) float smem[10240];
  float* const emb_s   = smem;                  // [TM][HID]
  float* const hch_s   = smem + TM * HID;       // [2TM][HID]
  float* const htild_s = smem + 3 * TM * HID;   // [TM][HID]
  float* const iou_s   = smem;                  // [TM][384] overlay
  float* const f_s     = smem + TM * 384;       // [2TM][HID] overlay
  __shared__ int   gnode_s[TM];
  __shared__ int   cbase_s[TM];
  __shared__ int   idx_s[TM];
  __shared__ float mf_s[TM];

  // ---- phase 0: per-node indices ----
  if (tid < TM) {
    int r = r0 + tid;
    bool valid = (r < R);
    int rr   = valid ? r : 0;
    int tree = rr >> level;
    int j    = rr & (nl - 1);
    int node = ps + j;
    int gnode = tree * TNODES + node;
    gnode_s[tid] = gnode;
    cbase_s[tid] = tree * TNODES + 2 * node + 1;   // left child (right = +1)
    int mk = valid ? mask[gnode]   : 0;
    int w  = valid ? wordid[gnode] : 0;
    idx_s[tid] = w * mk;
    mf_s[tid]  = (float)mk;
  }
  __syncthreads();

  // ---- phase 1: stage A operands into LDS ----
  {
    const float4* et = reinterpret_cast<const float4*>(emb_table);
    float4* es = reinterpret_cast<float4*>(emb_s);
    for (int e = tid; e < TM * (HID / 4); e += 256) {
      int m = e >> 5, k4 = e & 31;
      float4 v = et[idx_s[m] * (HID / 4) + k4];
      float s = mf_s[m];                 // fold maskf into emb (linear in the GEMM)
      v.x *= s; v.y *= s; v.z *= s; v.w *= s;
      es[e] = v;
    }
  }
  if (!LEAF) {
    const float4* hv = reinterpret_cast<const float4*>(h_out);
    float4* hs = reinterpret_cast<float4*>(hch_s);
    for (int e = tid; e < 2 * TM * (HID / 4); e += 256) {
      int row = e >> 5, k4 = e & 31;
      hs[e] = hv[(cbase_s[row >> 1] + (row & 1)) * (HID / 4) + k4];
    }
    __syncthreads();
    float4* ts = reinterpret_cast<float4*>(htild_s);
    for (int e = tid; e < TM * (HID / 4); e += 256) {
      int m = e >> 5, k4 = e & 31;
      float4 a = hs[(2 * m) * 32 + k4];
      float4 b = hs[(2 * m + 1) * 32 + k4];
      float4 sres; sres.x = a.x + b.x; sres.y = a.y + b.y; sres.z = a.z + b.z; sres.w = a.w + b.w;
      ts[e] = sres;
    }
  }
  __syncthreads();

  // ---- phase 2: register-blocked GEMMs ----
  const int tc = tid & 31;   // column group: 12 consecutive iou cols / 4 f cols
  const int tr = tid >> 5;   // row group: nodes 2*tr, 2*tr+1
  const int m0 = 2 * tr, m1 = m0 + 1;

  float acc0[12], acc1[12];
  #pragma unroll
  for (int u = 0; u < 12; ++u) { acc0[u] = 0.f; acc1[u] = 0.f; }

  {  // emb(masked) @ W_iou
    const float4* Wv = reinterpret_cast<const float4*>(W_iou + tc * 12);
    #pragma unroll 2
    for (int k = 0; k < HID; ++k) {
      float a0 = emb_s[m0 * HID + k];
      float a1 = emb_s[m1 * HID + k];
      float bb[12];
      *reinterpret_cast<float4*>(bb + 0) = Wv[k * 96 + 0];
      *reinterpret_cast<float4*>(bb + 4) = Wv[k * 96 + 1];
      *reinterpret_cast<float4*>(bb + 8) = Wv[k * 96 + 2];
      #pragma unroll
      for (int u = 0; u < 12; ++u) {
        acc0[u] = fmaf(a0, bb[u], acc0[u]);
        acc1[u] = fmaf(a1, bb[u], acc1[u]);
      }
    }
  }

  float accf[4][4];
  if (!LEAF) {
    {  // h_tild @ U_iou  (accumulates into the same iou accumulators)
      const float4* Uv = reinterpret_cast<const float4*>(U_iou + tc * 12);
      #pragma unroll 2
      for (int k = 0; k < HID; ++k) {
        float a0 = htild_s[m0 * HID + k];
        float a1 = htild_s[m1 * HID + k];
        float bb[12];
        *reinterpret_cast<float4*>(bb + 0) = Uv[k * 96 + 0];
        *reinterpret_cast<float4*>(bb + 4) = Uv[k * 96 + 1];
        *reinterpret_cast<float4*>(bb + 8) = Uv[k * 96 + 2];
        #pragma unroll
        for (int u = 0; u < 12; ++u) {
          acc0[u] = fmaf(a0, bb[u], acc0[u]);
          acc1[u] = fmaf(a1, bb[u], acc1[u]);
        }
      }
    }
    {  // child_h @ U_f_w : rows 4tr..4tr+3 (children of m0, m1), cols tc*4..tc*4+3
      #pragma unroll
      for (int i = 0; i < 4; ++i)
        #pragma unroll
        for (int jj = 0; jj < 4; ++jj) accf[i][jj] = 0.f;
      const float4* Fv = reinterpret_cast<const float4*>(U_f_w + tc * 4);
      #pragma unroll 2
      for (int k = 0; k < HID; ++k) {
        float4 b = Fv[k * 32];
        #pragma unroll
        for (int i = 0; i < 4; ++i) {
          float a = hch_s[(4 * tr + i) * HID + k];
          accf[i][0] = fmaf(a, b.x, accf[i][0]);
          accf[i][1] = fmaf(a, b.y, accf[i][1]);
          accf[i][2] = fmaf(a, b.z, accf[i][2]);
          accf[i][3] = fmaf(a, b.w, accf[i][3]);
        }
      }
    }
  }

  __syncthreads();   // all GEMM LDS reads complete before overlay writes

  {  // iou += b_iou, store pre-activation to LDS
    float bb[12];
    *reinterpret_cast<float4*>(bb + 0) = *reinterpret_cast<const float4*>(b_iou + tc * 12 + 0);
    *reinterpret_cast<float4*>(bb + 4) = *reinterpret_cast<const float4*>(b_iou + tc * 12 + 4);
    *reinterpret_cast<float4*>(bb + 8) = *reinterpret_cast<const float4*>(b_iou + tc * 12 + 8);
    #pragma unroll
    for (int u = 0; u < 12; ++u) {
      iou_s[m0 * 384 + tc * 12 + u] = acc0[u] + bb[u];
      iou_s[m1 * 384 + tc * 12 + u] = acc1[u] + bb[u];
    }
  }
  if (!LEAF) {
    float4 fb = *reinterpret_cast<const float4*>(U_f_b + tc * 4);
    float fbb[4] = {fb.x, fb.y, fb.z, fb.w};
    #pragma unroll
    for (int i = 0; i < 4; ++i)
      #pragma unroll
      for (int jj = 0; jj < 4; ++jj)
        f_s[(4 * tr + i) * HID + tc * 4 + jj] = fast_sigmoid(accf[i][jj] + fbb[jj]);
  }
  __syncthreads();

  // ---- phase 3: LSTM cell elementwise, write h (d_out) and c (ws) ----
  for (int e = tid; e < TM * HID; e += 256) {
    int m = e >> 7, d = e & 127;
    if (r0 + m >= R) continue;
    int gnode = gnode_s[m];
    float iv = iou_s[m * 384 + d];
    float ov = iou_s[m * 384 + 128 + d];
    float uv = iou_s[m * 384 + 256 + d];
    float cin;
    if (LEAF) {
      cin = c_init[gnode * HID + d];
    } else {
      int cb = cbase_s[m];
      cin = f_s[(2 * m) * HID + d]     * c_buf[cb * HID + d]
          + f_s[(2 * m + 1) * HID + d] * c_buf[(cb + 1) * HID + d];
    }
    float cn = fmaf(fast_sigmoid(iv), fast_tanh(uv), cin);
    float hn = fast_sigmoid(ov) * fast_tanh(cn);
    c_buf[gnode * HID + d] = cn;
    h_out[gnode * HID + d] = hn;
  }
}

__global__ void tail_copy_kernel(float* __restrict__ out) {
  int t = threadIdx.x;   // h_all[0] = h[tree0, node0, :]
  out[NTREES * TNODES * HID + t] = out[t];
}

extern "C" void kernel_launch(void* const* d_in, const int* in_sizes, int n_in,
                              void* d_out, int out_size, void* d_ws, size_t ws_size,
                              hipStream_t stream) {
  const int*   wordid  = (const int*)d_in[0];
  const int*   mask    = (const int*)d_in[1];
  // d_in[2] (h init) is never read by the reference computation
  const float* c_init  = (const float*)d_in[3];
  const float* emb     = (const float*)d_in[4];
  const float* W_iou   = (const float*)d_in[5];
  const float* U_iou   = (const float*)d_in[6];
  const float* b_iou   = (const float*)d_in[7];
  const float* U_f_w   = (const float*)d_in[8];
  const float* U_f_b   = (const float*)d_in[9];
  float* out   = (float*)d_out;
  float* c_buf = (float*)d_ws;   // NTREES*TNODES*HID floats = 134.2 MB

  for (int l = DEPTH - 1; l >= 0; --l) {
    int R = NTREES << l;
    int blocks = (R + TM - 1) / TM;
    if (l == DEPTH - 1) {
      tree_level_kernel<true><<<blocks, 256, 0, stream>>>(
          wordid, mask, c_init, emb, W_iou, U_iou, b_iou, U_f_w, U_f_b,
          out, c_buf, l);
    } else {
      tree_level_kernel<false><<<blocks, 256, 0, stream>>>(
          wordid, mask, c_init, emb, W_iou, U_iou, b_iou, U_f_w, U_f_b,
          out, c_buf, l);
    }
  }
  tail_copy_kernel<<<1, HID, 0, stream>>>(out);
}

// Round 2
// 526.384 us; speedup vs baseline: 3.2238x; 3.2238x over previous
//
#include <hip/hip_runtime.h>

#define HID    128
#define NTREES 8
#define DEPTH  15
#define TNODES 32767
#define TM     32

typedef __attribute__((ext_vector_type(8))) short bfrag8;   // 8 bf16 = 4 VGPR
typedef __attribute__((ext_vector_type(4))) float facc4;    // MFMA C/D
typedef __attribute__((ext_vector_type(4))) unsigned int u32x4;

__device__ __forceinline__ unsigned short f2b(float x) {
  union { float f; unsigned u; } a; a.f = x;
  unsigned r = a.u + 0x7fffu + ((a.u >> 16) & 1u);   // RNE
  return (unsigned short)(r >> 16);
}
__device__ __forceinline__ float b2f(unsigned short b) {
  union { float f; unsigned u; } a; a.u = ((unsigned)b) << 16;
  return a.f;
}
__device__ __forceinline__ float fast_sigmoid(float x) {
  return __builtin_amdgcn_rcpf(1.0f + __expf(-x));
}
__device__ __forceinline__ float fast_tanh(float x) {
  return 1.0f - 2.0f * __builtin_amdgcn_rcpf(1.0f + __expf(2.0f * x));
}

// pack 8 floats (scaled) to bf16 and store 16B at swizzled LDS byte offset
__device__ __forceinline__ void store8(char* base, int byte, const float* v, float sc) {
  union { unsigned short us[8]; u32x4 q; } p;
  #pragma unroll
  for (int i = 0; i < 8; ++i) p.us[i] = f2b(v[i] * sc);
  *(u32x4*)(base + byte) = p.q;
}

// Transpose+convert weights to bf16 [N][K] (k-contiguous) for MFMA B-fragments.
__global__ void prep_weights(const float* __restrict__ W_iou,
                             const float* __restrict__ U_iou,
                             const float* __restrict__ U_f_w,
                             unsigned short* __restrict__ Wt,
                             unsigned short* __restrict__ Ut,
                             unsigned short* __restrict__ Uft) {
  int i = blockIdx.x * 256 + threadIdx.x;
  if (i < 384 * HID) {
    int n = i >> 7, k = i & 127;
    Wt[i] = f2b(W_iou[k * 384 + n]);
    Ut[i] = f2b(U_iou[k * 384 + n]);
  }
  if (i < HID * HID) {
    int n = i >> 7, k = i & 127;
    Uft[i] = f2b(U_f_w[k * HID + n]);
  }
}

// One tree level, fused: gather+convert -> MFMA GEMMs -> LSTM cell.
// 256 thr = 4 waves. Wave w owns output dims [32w,32w+32) of iou AND f.
// LDS: staging emb[32][128]bf16 @0 (8K), htild @8K (8K), hch[64][128] @16K (16K);
// f_s fp32 [64][130] overlays everything after GEMMs (33.3K).
template <bool LEAF>
__global__ __launch_bounds__(256, 3)
void tree_level_mfma(const int* __restrict__ wordid,
                     const int* __restrict__ mask,
                     const float* __restrict__ c_init,
                     const float* __restrict__ emb_table,
                     const unsigned short* __restrict__ Wt,
                     const unsigned short* __restrict__ Ut,
                     const unsigned short* __restrict__ Uft,
                     const float* __restrict__ b_iou,
                     const float* __restrict__ U_f_b,
                     float* __restrict__ h_out,
                     const float* __restrict__ c_prev,
                     float* __restrict__ c_cur,
                     int level)
{
  __shared__ __align__(16) char smem[33792];
  __shared__ int gnode_s[TM], chb_s[TM], cpl_s[TM], idx_s[TM];
  __shared__ float mf_s[TM];

  const int tid = threadIdx.x;
  const int R  = NTREES << level;
  const int r0 = blockIdx.x * TM;

  // ---- per-node indices ----
  if (tid < TM) {
    int r  = r0 + tid;
    int rr = r < R ? r : R - 1;                 // clamp: padded lanes read safe rows
    int tree = rr >> level;
    int j    = rr & ((1 << level) - 1);
    int node = (1 << level) - 1 + j;
    int gn   = tree * TNODES + node;
    gnode_s[tid] = gn;
    chb_s[tid]   = gn + node + 1;               // left child gnode (= tree*T + 2*node+1)
    cpl_s[tid]   = (tree << (level + 1)) | (j << 1);  // left child slot in compact prev-c
    int mk = mask[gn];
    idx_s[tid] = wordid[gn] * mk;
    mf_s[tid]  = (float)mk;
  }
  __syncthreads();

  // ---- stage A operands (bf16, XOR-swizzled rows) ----
  for (int s = tid; s < TM * 16; s += 256) {        // emb (mask folded in)
    int m = s >> 4, sl = s & 15;
    const float* src = emb_table + (size_t)idx_s[m] * HID + sl * 8;
    float v[8];
    *(float4*)(v)     = *(const float4*)(src);
    *(float4*)(v + 4) = *(const float4*)(src + 4);
    int byte = (m * 256 + sl * 16) ^ ((m & 7) << 4);
    store8(smem, byte, v, mf_s[m]);
  }
  if (!LEAF) {
    for (int s = tid; s < 2 * TM * 16; s += 256) {  // children h
      int row = s >> 4, sl = s & 15;
      const float* src = h_out + (size_t)(chb_s[row >> 1] + (row & 1)) * HID + sl * 8;
      float v[8];
      *(float4*)(v)     = *(const float4*)(src);
      *(float4*)(v + 4) = *(const float4*)(src + 4);
      int byte = 16384 + ((row * 256 + sl * 16) ^ ((row & 7) << 4));
      store8(smem, byte, v, 1.0f);
    }
    __syncthreads();
    for (int s = tid; s < TM * 16; s += 256) {      // htild = ch0 + ch1
      int m = s >> 4, sl = s & 15;
      int b0 = 16384 + (((2 * m) * 256 + sl * 16) ^ (((2 * m) & 7) << 4));
      int b1 = 16384 + (((2 * m + 1) * 256 + sl * 16) ^ (((2 * m + 1) & 7) << 4));
      bfrag8 a = *(const bfrag8*)(smem + b0);
      bfrag8 b = *(const bfrag8*)(smem + b1);
      union { unsigned short us[8]; u32x4 q; } p;
      #pragma unroll
      for (int i = 0; i < 8; ++i)
        p.us[i] = f2b(b2f((unsigned short)a[i]) + b2f((unsigned short)b[i]));
      int byte = 8192 + ((m * 256 + sl * 16) ^ ((m & 7) << 4));
      *(u32x4*)(smem + byte) = p.q;
    }
  }
  __syncthreads();

  const int lane = tid & 63;
  const int w    = tid >> 6;
  const int lrow = lane & 15, lgrp = lane >> 4;

  // ---- iou GEMMs: emb@Wt (+ htild@Ut), wave w cols {g*8+2w, g*8+2w+1} g=i,o,u ----
  facc4 acc[2][6];
  #pragma unroll
  for (int rt = 0; rt < 2; ++rt)
    #pragma unroll
    for (int c = 0; c < 6; ++c)
      #pragma unroll
      for (int e = 0; e < 4; ++e) acc[rt][c][e] = 0.f;

  #pragma unroll
  for (int op = 0; op < (LEAF ? 1 : 2); ++op) {
    const char* abase = smem + op * 8192;
    const unsigned short* Bt = op ? Ut : Wt;
    #pragma unroll
    for (int k = 0; k < 4; ++k) {
      bfrag8 af[2];
      #pragma unroll
      for (int rt = 0; rt < 2; ++rt) {
        int row = rt * 16 + lrow;
        af[rt] = *(const bfrag8*)(abase + ((row * 256 + k * 64 + lgrp * 16) ^ ((row & 7) << 4)));
      }
      #pragma unroll
      for (int c = 0; c < 6; ++c) {
        int gct = (c >> 1) * 8 + 2 * w + (c & 1);
        bfrag8 bf = *(const bfrag8*)(Bt + (size_t)(gct * 16 + lrow) * HID + k * 32 + lgrp * 8);
        acc[0][c] = __builtin_amdgcn_mfma_f32_16x16x32_bf16(af[0], bf, acc[0][c], 0, 0, 0);
        acc[1][c] = __builtin_amdgcn_mfma_f32_16x16x32_bf16(af[1], bf, acc[1][c], 0, 0, 0);
      }
    }
  }

  // ---- f-gate GEMM: child_h @ Uft, then sigmoid -> f_s (overlay) ----
  if (!LEAF) {
    facc4 accf[4][2];
    #pragma unroll
    for (int rt = 0; rt < 4; ++rt)
      #pragma unroll
      for (int c = 0; c < 2; ++c)
        #pragma unroll
        for (int e = 0; e < 4; ++e) accf[rt][c][e] = 0.f;
    #pragma unroll
    for (int k = 0; k < 4; ++k) {
      bfrag8 af[4];
      #pragma unroll
      for (int rt = 0; rt < 4; ++rt) {
        int row = rt * 16 + lrow;
        af[rt] = *(const bfrag8*)(smem + 16384 + ((row * 256 + k * 64 + lgrp * 16) ^ ((row & 7) << 4)));
      }
      #pragma unroll
      for (int c = 0; c < 2; ++c) {
        bfrag8 bf = *(const bfrag8*)(Uft + (size_t)((2 * w + c) * 16 + lrow) * HID + k * 32 + lgrp * 8);
        #pragma unroll
        for (int rt = 0; rt < 4; ++rt)
          accf[rt][c] = __builtin_amdgcn_mfma_f32_16x16x32_bf16(af[rt], bf, accf[rt][c], 0, 0, 0);
      }
    }
    __syncthreads();                      // staging dead -> f_s overlay safe
    float* f_s = (float*)smem;            // [64][130]
    #pragma unroll
    for (int c = 0; c < 2; ++c) {
      int d = w * 32 + c * 16 + lrow;
      float fb = U_f_b[d];
      #pragma unroll
      for (int rt = 0; rt < 4; ++rt)
        #pragma unroll
        for (int reg = 0; reg < 4; ++reg) {
          int frow = rt * 16 + 4 * lgrp + reg;
          f_s[frow * 130 + d] = fast_sigmoid(accf[rt][c][reg] + fb);
        }
    }
  }

  // ---- LSTM cell epilogue (wave-local: own dims, f_s rows it wrote itself) ----
  const float* f_s = (const float*)smem;
  #pragma unroll
  for (int rt = 0; rt < 2; ++rt) {
    #pragma unroll
    for (int dt = 0; dt < 2; ++dt) {
      int d = w * 32 + dt * 16 + lrow;
      float bi = b_iou[d], bo = b_iou[HID + d], bu = b_iou[2 * HID + d];
      facc4 ci = acc[rt][0 + dt], co = acc[rt][2 + dt], cu = acc[rt][4 + dt];
      #pragma unroll
      for (int reg = 0; reg < 4; ++reg) {
        int m = rt * 16 + 4 * lgrp + reg;
        if (r0 + m >= R) continue;
        float iv = ci[reg] + bi, ov = co[reg] + bo, uv = cu[reg] + bu;
        float cin;
        if (LEAF) {
          cin = c_init[(size_t)gnode_s[m] * HID + d];
        } else {
          int cpl = cpl_s[m];
          cin = f_s[(2 * m) * 130 + d]     * c_prev[(size_t)cpl * HID + d]
              + f_s[(2 * m + 1) * 130 + d] * c_prev[(size_t)(cpl + 1) * HID + d];
        }
        float cn = fmaf(fast_sigmoid(iv), fast_tanh(uv), cin);
        float hn = fast_sigmoid(ov) * fast_tanh(cn);
        c_cur[(size_t)(r0 + m) * HID + d] = cn;
        int gn = gnode_s[m];
        h_out[(size_t)gn * HID + d] = hn;
        if (gn == 0) h_out[(size_t)NTREES * TNODES * HID + d] = hn;  // tail h_all[0]
      }
    }
  }
}

extern "C" void kernel_launch(void* const* d_in, const int* in_sizes, int n_in,
                              void* d_out, int out_size, void* d_ws, size_t ws_size,
                              hipStream_t stream) {
  const int*   wordid = (const int*)d_in[0];
  const int*   mask   = (const int*)d_in[1];
  const float* c_init = (const float*)d_in[3];
  const float* emb    = (const float*)d_in[4];
  const float* W_iou  = (const float*)d_in[5];
  const float* U_iou  = (const float*)d_in[6];
  const float* b_iou  = (const float*)d_in[7];
  const float* U_f_w  = (const float*)d_in[8];
  const float* U_f_b  = (const float*)d_in[9];
  float* out = (float*)d_out;

  char* ws = (char*)d_ws;
  unsigned short* Wt  = (unsigned short*)(ws);
  unsigned short* Ut  = (unsigned short*)(ws + 98304);
  unsigned short* Uft = (unsigned short*)(ws + 196608);
  float* bufA = (float*)(ws + 262144);               // 67.1 MB (leaf & even levels)
  float* bufB = (float*)(ws + 262144 + 67108864);    // 33.6 MB (odd levels)

  prep_weights<<<192, 256, 0, stream>>>(W_iou, U_iou, U_f_w, Wt, Ut, Uft);

  for (int l = DEPTH - 1; l >= 0; --l) {
    int R = NTREES << l;
    int blocks = (R + TM - 1) / TM;
    float* ccur  = ((DEPTH - 1 - l) & 1) ? bufB : bufA;
    float* cprev = ((DEPTH - 1 - l) & 1) ? bufA : bufB;
    if (l == DEPTH - 1)
      tree_level_mfma<true><<<blocks, 256, 0, stream>>>(
          wordid, mask, c_init, emb, Wt, Ut, Uft, b_iou, U_f_b, out, nullptr, ccur, l);
    else
      tree_level_mfma<false><<<blocks, 256, 0, stream>>>(
          wordid, mask, c_init, emb, Wt, Ut, Uft, b_iou, U_f_b, out, cprev, ccur, l);
  }
}